// Round 10
// baseline (313.184 us; speedup 1.0000x reference)
//
#include <hip/hip_runtime.h>

#define BB    16
#define TT    64
#define F0    8
#define NN    100
#define NEX   15
#define F1    32
#define F2    64
#define HRD   64
#define OUTD  5
#define BT    (BB*TT)        // 1024
#define MROWS (BT*NN)        // 102400
#define NK    14             // stored diffusion steps k'=1..14 (z15 unused)
#define ZELEMS  ((size_t)BT*F0*NK*NN)     // 11,468,800 floats (45.9 MB)
#define Y1ELEMS ((size_t)BT*F1*6*NN)      // 19,660,800 floats (78.6 MB)
#define Y2ELEMS ((size_t)BT*128*NN)       // 13,107,200 floats (52.4 MB)

// ===========================================================================
// Head v6: TWO chains per block (t0 = 1+2g, 2+2g), 256 threads, 52.8 KB LDS
// -> 2 blocks/CU (two independent barrier domains hide each other's stalls).
// Sld single-buffered (40 KB): per step issue S[t+1]->regs early, compute,
// barrier, ds_write S, barrier. zl double-buffered (no extra barrier).
// Thread = (f-half, m): 4 features x 2 chains -> 8 FMA per S value.
// Stores z_k' (k'=1..14) as [bt][f][k'-1][n] (coalesced over m).
// ===========================================================================
__global__ __launch_bounds__(256) void head_chain(
    const float* __restrict__ x, const float* __restrict__ S,
    float* __restrict__ zbuf) {
  __shared__ float Sld[NN * NN];        // 40 KB
  __shared__ float zl[2][2 * NN * F0];  // 2 buf x (2 chains x 100 x 8) = 12.8 KB

  const int blk = blockIdx.x;           // 512
  const int b   = blk >> 5;
  const int g   = blk & 31;
  const int tb  = 1 + 2 * g;            // chain A start; chain B starts tb+1
  const int te  = min(tb + 14, TT - 1); // last useful step (chain B k=13)
  const int tid = threadIdx.x;
  const int m   = tid & 127;
  const int f0b = (tid >> 7) * 4;

  // chain c = T - tb loads x[b, T-1] as its initial state into buffer dst
  auto act = [&](int T, int dst) {
    const int c = T - tb;
    if (c >= 0 && c < 2 && T <= TT - 1 && m < NN) {
#pragma unroll
      for (int j = 0; j < 4; ++j)
        zl[dst][c * 800 + m * F0 + f0b + j] =
            x[((size_t)(b * TT + T - 1) * F0 + f0b + j) * NN + m];
    }
  };

  // prologue: stage S[tb], activate chain A
  {
    const float4* Sg = (const float4*)(S + (size_t)(b * TT + tb) * NN * NN);
#pragma unroll
    for (int i = 0; i < 10; ++i) {
      const int idx = tid + i * 256;
      if (idx < 2500) *(float4*)&Sld[idx * 4] = Sg[idx];
    }
  }
  act(tb, 0);
  __syncthreads();

  int p = 0;
  for (int t = tb; t <= te; ++t, p ^= 1) {
    const bool more = (t < te);
    float4 Rn[10];
    if (more) {  // issue S[t+1] loads now; latency hidden under compute
      const float4* Sg =
          (const float4*)(S + (size_t)(b * TT + t + 1) * NN * NN);
#pragma unroll
      for (int i = 0; i < 10; ++i) {
        int idx = tid + i * 256; if (idx > 2499) idx = 2499;
        Rn[i] = Sg[idx];
      }
    }

    const bool a0 = (t - tb <= 13);                    // chain A active
    const bool a1 = (t > tb) && (tb + 1 <= TT - 1);    // chain B active

    float acc0[4] = {0.f, 0.f, 0.f, 0.f};
    float acc1[4] = {0.f, 0.f, 0.f, 0.f};
    if (m < NN) {
      const float* zA = &zl[p][f0b];
      const float* zB = &zl[p][800 + f0b];
      if (a0 && a1) {
#pragma unroll 10
        for (int n = 0; n < NN; ++n) {
          const float s = Sld[n * NN + m];
          const float4 z0 = *(const float4*)&zA[n * F0];
          const float4 z1 = *(const float4*)&zB[n * F0];
          acc0[0] += z0.x * s; acc0[1] += z0.y * s;
          acc0[2] += z0.z * s; acc0[3] += z0.w * s;
          acc1[0] += z1.x * s; acc1[1] += z1.y * s;
          acc1[2] += z1.z * s; acc1[3] += z1.w * s;
        }
      } else if (a0) {
#pragma unroll 10
        for (int n = 0; n < NN; ++n) {
          const float s = Sld[n * NN + m];
          const float4 z0 = *(const float4*)&zA[n * F0];
          acc0[0] += z0.x * s; acc0[1] += z0.y * s;
          acc0[2] += z0.z * s; acc0[3] += z0.w * s;
        }
      } else if (a1) {
#pragma unroll 10
        for (int n = 0; n < NN; ++n) {
          const float s = Sld[n * NN + m];
          const float4 z1 = *(const float4*)&zB[n * F0];
          acc1[0] += z1.x * s; acc1[1] += z1.y * s;
          acc1[2] += z1.z * s; acc1[3] += z1.w * s;
        }
      }
    }

    // new state -> other zl buffer; stores coalesced over m
    if (m < NN) {
      if (a0) {
        *(float4*)&zl[p ^ 1][m * F0 + f0b] =
            make_float4(acc0[0], acc0[1], acc0[2], acc0[3]);
        const int k = t - tb;                 // 0..13
#pragma unroll
        for (int j = 0; j < 4; ++j)
          zbuf[(((size_t)(b * TT + t) * F0 + f0b + j) * NK + k) * NN + m] =
              acc0[j];
      }
      if (a1) {
        *(float4*)&zl[p ^ 1][800 + m * F0 + f0b] =
            make_float4(acc1[0], acc1[1], acc1[2], acc1[3]);
        const int k = t - tb - 1;             // 0..13
#pragma unroll
        for (int j = 0; j < 4; ++j)
          zbuf[(((size_t)(b * TT + t) * F0 + f0b + j) * NK + k) * NN + m] =
              acc1[j];
      }
    }
    act(t + 1, p ^ 1);                        // chain B activation at t = tb

    if (more) {                               // block-uniform
      __syncthreads();                        // all Sld reads done
#pragma unroll
      for (int i = 0; i < 10; ++i) {
        const int idx = tid + i * 256;
        if (idx < 2500) *(float4*)&Sld[idx * 4] = Rn[i];
      }
      __syncthreads();                        // Sld[t+1] ready
    }
  }
}

// ===========================================================================
// conv1: thread-per-row, co chunk of 8 (gridDim.y=4). ROLLED ci loop
// (full unroll = I$ thrash, R8). Loads lane-coalesced dwords; weights
// wave-uniform s_loads. Writes y1 [bt][co][p][n].
// ===========================================================================
__global__ __launch_bounds__(256) void conv1_k(
    const float* __restrict__ x, const float* __restrict__ zbuf,
    const float* __restrict__ w1, const float* __restrict__ b1,
    float* __restrict__ y1g) {
  const int row = blockIdx.x * 256 + threadIdx.x;
  const int bt  = row / NN;
  const int n   = row - bt * NN;
  const int t   = bt & (TT - 1);
  const int c0  = blockIdx.y * 8;

  float acc[8][12];
#pragma unroll
  for (int j = 0; j < 8; ++j) {
    const float bias = b1[c0 + j];
#pragma unroll
    for (int l = 0; l < 12; ++l) acc[j][l] = bias;
  }

#pragma unroll 1
  for (int ci = 0; ci < F0; ++ci) {
    float zv[15];
    zv[0] = x[((size_t)bt * F0 + ci) * NN + n];
#pragma unroll
    for (int k = 1; k < 15; ++k)
      zv[k] = (k <= t)
          ? zbuf[(((size_t)bt * F0 + ci) * NK + (k - 1)) * NN + n]
          : 0.f;
#pragma unroll
    for (int j = 0; j < 8; ++j)
#pragma unroll
      for (int kk = 0; kk < 4; ++kk) {
        const float w = w1[((c0 + j) * F0 + ci) * 4 + kk];   // uniform
#pragma unroll
        for (int l = 0; l < 12; ++l) acc[j][l] += zv[l + kk] * w;
      }
  }

#pragma unroll
  for (int j = 0; j < 8; ++j)
#pragma unroll
    for (int p = 0; p < 6; ++p)
      y1g[((size_t)bt * (F1 * 6) + (c0 + j) * 6 + p) * NN + n] =
          fmaxf(fmaxf(acc[j][2 * p], acc[j][2 * p + 1]), 0.f);
}

// ===========================================================================
// conv2: thread-per-row, co chunk of 32 (gridDim.y=2) — halves y1 re-reads
// vs 16-chunk and doubles FMA per load. ROLLED ci loop (~3.5 KB body).
// Writes y2 [bt][d=128][n].
// ===========================================================================
__global__ __launch_bounds__(256) void conv2_k(
    const float* __restrict__ y1g,
    const float* __restrict__ w2, const float* __restrict__ b2,
    float* __restrict__ y2g) {
  const int row = blockIdx.x * 256 + threadIdx.x;
  const int bt  = row / NN;
  const int n   = row - bt * NN;
  const int cc  = blockIdx.y * 32;

  float acc[32][4];
#pragma unroll
  for (int j = 0; j < 32; ++j) {
    const float bb = b2[cc + j];
#pragma unroll
    for (int l = 0; l < 4; ++l) acc[j][l] = bb;
  }

#pragma unroll 1
  for (int ci = 0; ci < F1; ++ci) {
    float yv[6];
#pragma unroll
    for (int l = 0; l < 6; ++l)
      yv[l] = y1g[((size_t)bt * (F1 * 6) + ci * 6 + l) * NN + n];
#pragma unroll
    for (int j = 0; j < 32; ++j)
#pragma unroll
      for (int kk = 0; kk < 3; ++kk) {
        const float w = w2[((cc + j) * F1 + ci) * 3 + kk];   // uniform
#pragma unroll
        for (int l = 0; l < 4; ++l) acc[j][l] += yv[l + kk] * w;
      }
  }

#pragma unroll
  for (int j = 0; j < 32; ++j) {
    y2g[((size_t)bt * 128 + (cc + j) * 2 + 0) * NN + n] =
        fmaxf(fmaxf(acc[j][0], acc[j][1]), 0.f);
    y2g[((size_t)bt * 128 + (cc + j) * 2 + 1) * NN + n] =
        fmaxf(fmaxf(acc[j][2], acc[j][3]), 0.f);
  }
}

// ===========================================================================
// fc: thread-per-row. v[128] coalesced dword loads; fc1 j-loop (rolled) with
// contiguous uniform fw1 rows (s_loads); fc2 folded into the j-loop.
// ===========================================================================
__global__ __launch_bounds__(256) void fc_k(
    const float* __restrict__ y2g,
    const float* __restrict__ fw1, const float* __restrict__ fb1,
    const float* __restrict__ fw2, const float* __restrict__ fb2,
    float* __restrict__ out) {
  const int row = blockIdx.x * 256 + threadIdx.x;
  const int bt  = row / NN;
  const int n   = row - bt * NN;
  const float* yi = y2g + (size_t)bt * 128 * NN + n;

  float v[128];
#pragma unroll
  for (int d = 0; d < 128; ++d) v[d] = yi[(size_t)d * NN];

  float o[OUTD];
#pragma unroll
  for (int q = 0; q < OUTD; ++q) o[q] = fb2[q];

#pragma unroll 1
  for (int j = 0; j < HRD; ++j) {
    const float* wr = fw1 + j * 128;     // uniform, contiguous -> s_loads
    float s0 = 0.f, s1 = 0.f, s2 = 0.f, s3 = 0.f;
#pragma unroll
    for (int d = 0; d < 128; d += 4) {
      s0 += v[d + 0] * wr[d + 0];
      s1 += v[d + 1] * wr[d + 1];
      s2 += v[d + 2] * wr[d + 2];
      s3 += v[d + 3] * wr[d + 3];
    }
    const float h = fmaxf((s0 + s1) + (s2 + s3) + fb1[j], 0.f);
#pragma unroll
    for (int q = 0; q < OUTD; ++q) o[q] += h * fw2[q * HRD + j];
  }
#pragma unroll
  for (int q = 0; q < OUTD; ++q)
    out[((size_t)bt * OUTD + q) * NN + n] = o[q];
}

// ===========================================================================
extern "C" void kernel_launch(void* const* d_in, const int* in_sizes, int n_in,
                              void* d_out, int out_size, void* d_ws,
                              size_t ws_size, hipStream_t stream) {
  const float* x   = (const float*)d_in[0];
  const float* S   = (const float*)d_in[1];
  const float* w1  = (const float*)d_in[2];
  const float* b1  = (const float*)d_in[3];
  const float* w2  = (const float*)d_in[4];
  const float* b2  = (const float*)d_in[5];
  const float* fw1 = (const float*)d_in[6];
  const float* fb1 = (const float*)d_in[7];
  const float* fw2 = (const float*)d_in[8];
  const float* fb2 = (const float*)d_in[9];

  float* zbuf = (float*)d_ws;                 // 45.9 MB
  float* y1g  = zbuf + ZELEMS;                // 78.6 MB
  float* y2g  = y1g + Y1ELEMS;                // 52.4 MB  (total 176.9 MB)
  float* outp = (float*)d_out;

  head_chain<<<BB * 32, 256, 0, stream>>>(x, S, zbuf);
  conv1_k<<<dim3(MROWS / 256, 4), 256, 0, stream>>>(x, zbuf, w1, b1, y1g);
  conv2_k<<<dim3(MROWS / 256, 2), 256, 0, stream>>>(y1g, w2, b2, y2g);
  fc_k<<<MROWS / 256, 256, 0, stream>>>(y2g, fw1, fb1, fw2, fb2, outp);
}